// Round 6
// baseline (190.956 us; speedup 1.0000x reference)
//
#include <hip/hip_runtime.h>
#include <hip/hip_bf16.h>
#include <math.h>

#define BB 128
#define MM 200
#define SS 20
#define DD 128
#define NC 10000
#define CL 10
#define LCT 64          // logits cand-tile
#define NROW (BB * MM)  // 25600 story rows
#define NV 100000

// k_gather block ranges: story row-sums FIRST (the long pole: 512K row
// gathers, ~262 MB logical / ~51 MB unique), then cand row-sums (~51 MB
// unique from W), queries last. All zero-LDS, all overlap.
#define STY_OFF 0
#define STY_BLK (NROW / 8)   // 3200: story rows, 8 rows x 32 lanes
#define CND_OFF STY_BLK
#define CND_BLK (NC / 8)     // 1250: cand row-sums, 8 rows x 32 lanes
#define QRY_OFF (CND_OFF + CND_BLK)
#define QRY_BLK (BB / 16)    // 8: query row-sums (exact f32)
#define GTH_BLK (QRY_OFF + QRY_BLK)

__device__ __forceinline__ unsigned pack_bf16(float a, float b) {
    unsigned ua = __float_as_uint(a), ub = __float_as_uint(b);
    ua += 0x7fff + ((ua >> 16) & 1);  // RNE; inputs finite
    ub += 0x7fff + ((ub >> 16) & 1);
    return (ua >> 16) | (ub & 0xffff0000u);
}
__device__ __forceinline__ float bflo(unsigned v) { return __uint_as_float(v << 16); }
__device__ __forceinline__ float bfhi(unsigned v) { return __uint_as_float(v & 0xffff0000u); }

// Per-block index-width detection: odd 32-bit words of queries are the high
// halves iff indices are int64 (tokens < 2^32 -> all zero). For int32 they are
// real tokens (P(zero) = 1e-5 each). 8 broadcast loads, no extra dispatch.
__device__ __forceinline__ int detect_shift(const int* __restrict__ q) {
    int zc = 0;
#pragma unroll
    for (int i = 0; i < 8; ++i) zc += (q[2 * i + 1] == 0);
    return (zc >= 6) ? 1 : 0;
}

// Single zero-LDS gather kernel. r4's decisive null (halving story-row bytes
// 256->128 B changed end-to-end by ~0) showed gather time is insensitive to
// row width here -- so gather straight from f32 A (exact, masked) and delete
// the quant pass (~9 us streaming + a launch gap + the serial dependency).
//  [0, 3200):      story row-sums from f32 A -> m_all (packed bf16)
//  [3200, 4450):   candidate row-sums from f32 W -> cand_buf
//  [4450, 4458):   query row-sums from f32 A -> u0_all
__global__ __launch_bounds__(256) void k_gather(const int* __restrict__ stories,
                                                const int* __restrict__ queries,
                                                const int* __restrict__ cands,
                                                const float* __restrict__ A,
                                                const float* __restrict__ W,
                                                unsigned* __restrict__ m_all,
                                                float* __restrict__ u0_all,
                                                float* __restrict__ cand_buf) {
    int bid = blockIdx.x;
    int tid = threadIdx.x;
    int shift = detect_shift(queries);

    if (bid < CND_OFF) {
        // ---- Story rows: 8 rows/block, 32 lanes/row, lane = float4 (4 dims).
        //      A row 0 is NOT zeroed -> mask tok==0 (padding_idx). ----
        int g = tid >> 5, l = tid & 31;
        int r = bid * 8 + g;
        float a0 = 0.f, a1 = 0.f, a2 = 0.f, a3 = 0.f;
#pragma unroll
        for (int s = 0; s < SS; ++s) {
            int tok = stories[((size_t)(r * SS + s)) << shift];
            float4 v = ((const float4*)(A + (size_t)(unsigned)tok * DD))[l];
            float msk = tok ? 1.f : 0.f;
            a0 = fmaf(msk, v.x, a0);
            a1 = fmaf(msk, v.y, a1);
            a2 = fmaf(msk, v.z, a2);
            a3 = fmaf(msk, v.w, a3);
        }
        uint2 o;
        o.x = pack_bf16(a0, a1);
        o.y = pack_bf16(a2, a3);
        ((uint2*)(m_all + (size_t)r * (DD / 2)))[l] = o;  // 256 B/row coalesced
    } else if (bid < QRY_OFF) {
        // ---- Candidate row-sums from f32 W (masked; W row 0 not zeroed) ----
        int g = tid >> 5, l = tid & 31;
        int row = (bid - CND_OFF) * 8 + g;
        int toks[CL];
#pragma unroll
        for (int s = 0; s < CL; ++s)
            toks[s] = cands[((size_t)(row * CL + s)) << shift];
        float4 acc = make_float4(0.f, 0.f, 0.f, 0.f);
#pragma unroll
        for (int s = 0; s < CL; ++s) {
            float4 v = ((const float4*)(W + (size_t)(unsigned)toks[s] * DD))[l];
            float msk = toks[s] ? 1.f : 0.f;
            acc.x = fmaf(msk, v.x, acc.x);
            acc.y = fmaf(msk, v.y, acc.y);
            acc.z = fmaf(msk, v.z, acc.z);
            acc.w = fmaf(msk, v.w, acc.w);
        }
        ((float4*)(cand_buf + (size_t)row * DD))[l] = acc;
    } else {
        // ---- Query rows: u0[b,:] = sum_s A[q[b,s]][:], exact f32, masked ----
        int g = tid >> 4, l = tid & 15;
        int b = (bid - QRY_OFF) * 16 + g;
        float a[8] = {0.f, 0.f, 0.f, 0.f, 0.f, 0.f, 0.f, 0.f};
#pragma unroll
        for (int s = 0; s < SS; ++s) {
            int tok = queries[((size_t)(b * SS + s)) << shift];
            const float4* vp = (const float4*)(A + (size_t)(unsigned)tok * DD) + l * 2;
            float4 v0 = vp[0], v1 = vp[1];
            float msk = tok ? 1.f : 0.f;
            a[0] = fmaf(msk, v0.x, a[0]); a[1] = fmaf(msk, v0.y, a[1]);
            a[2] = fmaf(msk, v0.z, a[2]); a[3] = fmaf(msk, v0.w, a[3]);
            a[4] = fmaf(msk, v1.x, a[4]); a[5] = fmaf(msk, v1.y, a[5]);
            a[6] = fmaf(msk, v1.z, a[6]); a[7] = fmaf(msk, v1.w, a[7]);
        }
        float4* op = (float4*)(u0_all + (size_t)b * DD + l * 8);
        op[0] = make_float4(a[0], a[1], a[2], a[3]);
        op[1] = make_float4(a[4], a[5], a[6], a[7]);
    }
}

// One block per batch: stream m_all[b] (51.2 KB, coalesced) into LDS, load
// u0, run 3 fused hops, write uT column. (Known-good r0 hop pipeline.)
__global__ __launch_bounds__(512) void k_hops(const unsigned* __restrict__ m_all,
                                              const float* __restrict__ u0_all,
                                              const float* __restrict__ Hw,
                                              float* __restrict__ uT) {
    __shared__ unsigned m_s[MM][DD / 2];  // packed bf16 pairs, 51.2 KB
    __shared__ float u_s[DD];
    __shared__ float p_s[MM];
    __shared__ float o_part[8][DD];
    __shared__ float red_s;

    int b = blockIdx.x;
    int tid = threadIdx.x;

    {
        const uint4* src = (const uint4*)(m_all + (size_t)b * MM * (DD / 2));
        uint4* dst = (uint4*)&m_s[0][0];
        for (int i = tid; i < MM * (DD / 2) / 4; i += 512) dst[i] = src[i];
    }
    if (tid < DD) u_s[tid] = u0_all[(size_t)b * DD + tid];
    __syncthreads();

    for (int hop = 0; hop < 3; ++hop) {
        // Phase 1: p[t] = m[t,:] . u — thread per row, rotated (conflict-free)
        if (tid < MM) {
            const float2* u2 = (const float2*)u_s;
            float acc = 0.f;
#pragma unroll 8
            for (int li = 0; li < 64; ++li) {
                int j = (tid + li) & 63;
                unsigned pv = m_s[tid][j];
                float2 uv = u2[j];
                acc += bflo(pv) * uv.x + bfhi(pv) * uv.y;
            }
            p_s[tid] = acc;
        }
        __syncthreads();
        // Softmax over 200 (wave 0; 1/sum deferred to phase 3)
        if (tid < 64) {
            float v0 = p_s[tid], v1 = p_s[tid + 64], v2 = p_s[tid + 128];
            float v3 = (tid < 8) ? p_s[tid + 192] : -1e30f;
            float mx = fmaxf(fmaxf(v0, v1), fmaxf(v2, v3));
            for (int off = 32; off; off >>= 1) mx = fmaxf(mx, __shfl_down(mx, off));
            mx = __shfl(mx, 0);
            float e0 = __expf(v0 - mx), e1 = __expf(v1 - mx), e2 = __expf(v2 - mx);
            float e3 = (tid < 8) ? __expf(v3 - mx) : 0.f;
            float sm = e0 + e1 + e2 + e3;
            for (int off = 32; off; off >>= 1) sm += __shfl_down(sm, off);
            p_s[tid] = e0;
            p_s[tid + 64] = e1;
            p_s[tid + 128] = e2;
            if (tid < 8) p_s[tid + 192] = e3;
            if (tid == 0) red_s = 1.f / __shfl(sm, 0);
        }
        __syncthreads();
        // Phase 2: o[d] = sum_mm e[mm]*m[mm,d], mm split 8 ways
        {
            int c = tid & 63, h = tid >> 6;
            int mm0 = h * 25;
            float ax = 0.f, ay = 0.f;
#pragma unroll 5
            for (int k = 0; k < 25; ++k) {
                unsigned pv = m_s[mm0 + k][c];
                float p = p_s[mm0 + k];
                ax = fmaf(p, bflo(pv), ax);
                ay = fmaf(p, bfhi(pv), ay);
            }
            o_part[h][2 * c] = ax;
            o_part[h][2 * c + 1] = ay;
        }
        __syncthreads();
        // Phase 3: u'[d] = tanh( Hw[d,:] . u + inv * o[d] )
        float u_new = 0.f;
        if (tid < DD) {
            float o = 0.f;
#pragma unroll
            for (int h = 0; h < 8; ++h) o += o_part[h][tid];
            float acc = o * red_s;
            const float4* hrow = (const float4*)(Hw + tid * DD);
            const float4* u4 = (const float4*)u_s;
#pragma unroll 8
            for (int j = 0; j < DD / 4; ++j) {
                float4 hv = hrow[j];
                float4 uv = u4[j];
                acc += hv.x * uv.x + hv.y * uv.y + hv.z * uv.z + hv.w * uv.w;
            }
            u_new = tanhf(acc);
        }
        __syncthreads();
        if (tid < DD) u_s[tid] = u_new;
        __syncthreads();
    }
    if (tid < DD) uT[tid * BB + b] = u_s[tid];
}

// logits[b,c] = u[b,:] . cand_sum[c,:]. Grid (157, 4): block = 32 batches x
// 64 cands, 256 threads, thread = 1-batch x 8-cand tile. 628 blocks = 2.45
// waves/SIMD (r5: proven +3.6 us over the 157-block version). Cand tile
// transposed to k-major in LDS (pad 68); u read is one coalesced 128 B line
// per wave-half (uT is [d][B], L2-resident).
__global__ __launch_bounds__(256) void k_logits(const float* __restrict__ uT,
                                                const float* __restrict__ cs,
                                                float* __restrict__ out) {
    __shared__ float c_s[DD][LCT + 4];  // [k][c], 34.8 KB
    int c0 = blockIdx.x * LCT;
    int b0 = blockIdx.y * 32;
    int tid = threadIdx.x;
    {
        int c = tid >> 2, l = tid & 3;  // c 0..63, l = k-quarter
        int row = c0 + c;
        if (row >= NC) row = NC - 1;
        const float4* rp = (const float4*)(cs + (size_t)row * DD);
#pragma unroll
        for (int i = 0; i < 8; ++i) {
            int k = (l << 5) + (i << 2);
            float4 v = rp[(l << 3) + i];
            c_s[k][c] = v.x;
            c_s[k + 1][c] = v.y;
            c_s[k + 2][c] = v.z;
            c_s[k + 3][c] = v.w;
        }
    }
    __syncthreads();
    int tx = tid & 31, ty = tid >> 5;  // tx: batch, ty: 8-cand group
    const float* cb = &c_s[0][ty << 3];
    const float* up = uT + b0 + tx;
    float acc[8];
#pragma unroll
    for (int j = 0; j < 8; ++j) acc[j] = 0.f;
#pragma unroll 4
    for (int k = 0; k < DD; ++k) {
        float u = up[k * BB];
        float4 ca = *(const float4*)(cb + k * (LCT + 4));
        float4 cc = *(const float4*)(cb + k * (LCT + 4) + 4);
        acc[0] = fmaf(u, ca.x, acc[0]);
        acc[1] = fmaf(u, ca.y, acc[1]);
        acc[2] = fmaf(u, ca.z, acc[2]);
        acc[3] = fmaf(u, ca.w, acc[3]);
        acc[4] = fmaf(u, cc.x, acc[4]);
        acc[5] = fmaf(u, cc.y, acc[5]);
        acc[6] = fmaf(u, cc.z, acc[6]);
        acc[7] = fmaf(u, cc.w, acc[7]);
    }
    if (c0 + (ty << 3) < NC) {  // NC % 8 == 0 -> whole 8-chunk valid
        float* orow = out + (size_t)(b0 + tx) * NC + c0 + (ty << 3);
        ((float4*)orow)[0] = make_float4(acc[0], acc[1], acc[2], acc[3]);
        ((float4*)orow)[1] = make_float4(acc[4], acc[5], acc[6], acc[7]);
    }
}

extern "C" void kernel_launch(void* const* d_in, const int* in_sizes, int n_in,
                              void* d_out, int out_size, void* d_ws, size_t ws_size,
                              hipStream_t stream) {
    const int* stories = (const int*)d_in[0];       // [128,200,20] tokens
    const int* queries = (const int*)d_in[1];       // [128,20]
    const int* cands   = (const int*)d_in[2];       // [10000,10]
    const float* A  = (const float*)d_in[3];        // f32 [100000,128]
    const float* W  = (const float*)d_in[4];        // f32 [100000,128]
    const float* Hw = (const float*)d_in[5];        // f32 [128,128]
    float* out = (float*)d_out;                     // f32 [128,10000]

    float* cand_buf = (float*)d_ws;                          // 5.12 MB
    float* uT_buf = cand_buf + (size_t)NC * DD;              // 64 KB
    float* u0_buf = uT_buf + (size_t)BB * DD;                // 64 KB
    unsigned* m_all = (unsigned*)(u0_buf + (size_t)BB * DD); // 6.55 MB (~11.9 MB total)

    k_gather<<<GTH_BLK, 256, 0, stream>>>(stories, queries, cands, A, W,
                                          m_all, u0_buf, cand_buf);
    k_hops<<<BB, 512, 0, stream>>>(m_all, u0_buf, Hw, uT_buf);
    dim3 lgrid((NC + LCT - 1) / LCT, 4);
    k_logits<<<lgrid, 256, 0, stream>>>(uT_buf, cand_buf, out);
}

// Round 7
// 181.854 us; speedup vs baseline: 1.0500x; 1.0500x over previous
//
#include <hip/hip_runtime.h>
#include <hip/hip_bf16.h>
#include <math.h>

#define BB 128
#define MM 200
#define SS 20
#define DD 128
#define NC 10000
#define CL 10
#define LCT 64          // logits cand-tile
#define NROW (BB * MM)  // 25600 story rows
#define NV 100000

// k_prep block ranges: cand gathers FIRST (latency-bound long pole starts at
// t=0 and overlaps the streaming quant), then A-quant, queries last.
#define CND_OFF 0
#define CND_BLK (NC / 8)     // 1250: cand row-sums
#define CONV_OFF CND_BLK
#define CONV_BLK (NV / 16)   // 6250: A -> int8 quant, 16 rows x 16 lanes
#define QRY_OFF (CONV_OFF + CONV_BLK)
#define QRY_BLK (BB / 16)    // 8: query row-sums (exact f32)
#define PREP_BLK (QRY_OFF + QRY_BLK)
#define SG_BLK (NROW / 32)   // 800: story gather, 32 rows x 8 lanes

__device__ __forceinline__ unsigned pack_bf16(float a, float b) {
    unsigned ua = __float_as_uint(a), ub = __float_as_uint(b);
    ua += 0x7fff + ((ua >> 16) & 1);  // RNE; inputs finite
    ub += 0x7fff + ((ub >> 16) & 1);
    return (ua >> 16) | (ub & 0xffff0000u);
}
__device__ __forceinline__ float bflo(unsigned v) { return __uint_as_float(v << 16); }
__device__ __forceinline__ float bfhi(unsigned v) { return __uint_as_float(v & 0xffff0000u); }

// Per-block index-width detection: odd 32-bit words of queries are the high
// halves iff indices are int64 (tokens < 2^32 -> all zero). For int32 they are
// real tokens (P(zero) = 1e-5 each). 8 broadcast loads, no extra dispatch.
__device__ __forceinline__ int detect_shift(const int* __restrict__ q) {
    int zc = 0;
#pragma unroll
    for (int i = 0; i < 8; ++i) zc += (q[2 * i + 1] == 0);
    return (zc >= 6) ? 1 : 0;
}

// Accumulate 4 int8 lanes of word w scaled by s into a[0..3].
__device__ __forceinline__ void acc_i8(unsigned w, float s, float* a) {
    a[0] = fmaf(s, (float)(int)(signed char)(w & 0xffu), a[0]);
    a[1] = fmaf(s, (float)(int)(signed char)((w >> 8) & 0xffu), a[1]);
    a[2] = fmaf(s, (float)(int)(signed char)((w >> 16) & 0xffu), a[2]);
    a[3] = fmaf(s, (float)(int)(signed char)(w >> 24), a[3]);
}

// Zero-LDS prep kernel, three independent block ranges:
//  [0, 1250):      candidate row-sums from f32 W (masked) — the latency-bound
//                  long pole, dispatched first so it overlaps the quant.
//  [1250, 7500):   A f32 -> int8 + per-row scale (row 0 forced to zero).
//  [7500, 7508):   query row-sums directly from f32 A (exact, masked).
// (r6 control: gathering stories straight from f32 A instead costs +8 us and
// +64 MB FETCH — 512 B rows defeat L3 absorption. 128 B int8 rows + this
// overlapped quant is the measured optimum.)
__global__ __launch_bounds__(256) void k_prep(const float* __restrict__ A,
                                              const float* __restrict__ W,
                                              const int* __restrict__ queries,
                                              const int* __restrict__ cands,
                                              unsigned char* __restrict__ Ai8,
                                              float* __restrict__ sc,
                                              float* __restrict__ u0_all,
                                              float* __restrict__ cand_buf) {
    int bid = blockIdx.x;
    int tid = threadIdx.x;

    if (bid < CONV_OFF) {
        // ---- Candidate row-sums from f32 W (masked; W row 0 not zeroed) ----
        int shift = detect_shift(queries);
        int g = tid >> 5, l = tid & 31;
        int row = (bid - CND_OFF) * 8 + g;
        int toks[CL];
#pragma unroll
        for (int s = 0; s < CL; ++s)
            toks[s] = cands[((size_t)(row * CL + s)) << shift];
        float4 acc = make_float4(0.f, 0.f, 0.f, 0.f);
#pragma unroll
        for (int s = 0; s < CL; ++s) {
            float4 v = ((const float4*)(W + (size_t)(unsigned)toks[s] * DD))[l];
            float msk = toks[s] ? 1.f : 0.f;
            acc.x = fmaf(msk, v.x, acc.x);
            acc.y = fmaf(msk, v.y, acc.y);
            acc.z = fmaf(msk, v.z, acc.z);
            acc.w = fmaf(msk, v.w, acc.w);
        }
        ((float4*)(cand_buf + (size_t)row * DD))[l] = acc;
    } else if (bid < QRY_OFF) {
        // ---- int8 quant: 16 rows/block, 16 lanes/row (8 dims each) ----
        int g = tid >> 4, l = tid & 15;
        int row = (bid - CONV_OFF) * 16 + g;
        const float4* rp = (const float4*)(A + (size_t)row * DD) + l * 2;
        float4 x0 = rp[0], x1 = rp[1];
        float am = fmaxf(fmaxf(fmaxf(fabsf(x0.x), fabsf(x0.y)),
                               fmaxf(fabsf(x0.z), fabsf(x0.w))),
                         fmaxf(fmaxf(fabsf(x1.x), fabsf(x1.y)),
                               fmaxf(fabsf(x1.z), fabsf(x1.w))));
#pragma unroll
        for (int m = 1; m < 16; m <<= 1) am = fmaxf(am, __shfl_xor(am, m, 16));
        float s = am * (1.f / 127.f);
        float inv = (am > 0.f) ? 127.f / am : 0.f;
        int q0 = __float2int_rn(x0.x * inv), q1 = __float2int_rn(x0.y * inv);
        int q2 = __float2int_rn(x0.z * inv), q3 = __float2int_rn(x0.w * inv);
        int q4 = __float2int_rn(x1.x * inv), q5 = __float2int_rn(x1.y * inv);
        int q6 = __float2int_rn(x1.z * inv), q7 = __float2int_rn(x1.w * inv);
        uint2 o;
        o.x = (q0 & 255) | ((q1 & 255) << 8) | ((q2 & 255) << 16) |
              ((unsigned)(q3 & 255) << 24);
        o.y = (q4 & 255) | ((q5 & 255) << 8) | ((q6 & 255) << 16) |
              ((unsigned)(q7 & 255) << 24);
        if (row == 0) {  // padding_idx row must be zero
            o.x = 0u;
            o.y = 0u;
            s = 0.f;
        }
        ((uint2*)Ai8)[(size_t)row * 16 + l] = o;
        if (l == 0) sc[row] = s;
    } else {
        // ---- Query rows: u0[b,:] = sum_s A[q[b,s]][:], exact f32, masked ----
        int shift = detect_shift(queries);
        int g = tid >> 4, l = tid & 15;
        int b = (bid - QRY_OFF) * 16 + g;
        float a[8] = {0.f, 0.f, 0.f, 0.f, 0.f, 0.f, 0.f, 0.f};
#pragma unroll
        for (int s = 0; s < SS; ++s) {
            int tok = queries[((size_t)(b * SS + s)) << shift];
            const float4* vp = (const float4*)(A + (size_t)(unsigned)tok * DD) + l * 2;
            float4 v0 = vp[0], v1 = vp[1];
            float msk = tok ? 1.f : 0.f;
            a[0] = fmaf(msk, v0.x, a[0]); a[1] = fmaf(msk, v0.y, a[1]);
            a[2] = fmaf(msk, v0.z, a[2]); a[3] = fmaf(msk, v0.w, a[3]);
            a[4] = fmaf(msk, v1.x, a[4]); a[5] = fmaf(msk, v1.y, a[5]);
            a[6] = fmaf(msk, v1.z, a[6]); a[7] = fmaf(msk, v1.w, a[7]);
        }
        float4* op = (float4*)(u0_all + (size_t)b * DD + l * 8);
        op[0] = make_float4(a[0], a[1], a[2], a[3]);
        op[1] = make_float4(a[4], a[5], a[6], a[7]);
    }
}

// Story row-sums from the int8 table: 32 rows/block, 8 lanes/row, lane =
// uint4 (16 dims). 128 B/row gathered + 4 B scale (L2-resident table).
// Dequant-fma on the idle VALU; pack bf16 -> m_all.
__global__ __launch_bounds__(256) void k_sgather(const int* __restrict__ stories,
                                                 const int* __restrict__ queries,
                                                 const unsigned char* __restrict__ Ai8,
                                                 const float* __restrict__ sc,
                                                 unsigned* __restrict__ m_all) {
    int bid = blockIdx.x;
    int tid = threadIdx.x;
    int shift = detect_shift(queries);
    int g = tid >> 3, l = tid & 7;
    int r = bid * 32 + g;

    float a[16];
#pragma unroll
    for (int i = 0; i < 16; ++i) a[i] = 0.f;
#pragma unroll
    for (int s = 0; s < SS; ++s) {
        int tok = stories[((size_t)(r * SS + s)) << shift];
        uint4 v = ((const uint4*)Ai8)[(size_t)(unsigned)tok * 8 + l];
        float st = sc[(unsigned)tok];
        acc_i8(v.x, st, a + 0);
        acc_i8(v.y, st, a + 4);
        acc_i8(v.z, st, a + 8);
        acc_i8(v.w, st, a + 12);
    }
    uint4 o0, o1;
    o0.x = pack_bf16(a[0], a[1]);
    o0.y = pack_bf16(a[2], a[3]);
    o0.z = pack_bf16(a[4], a[5]);
    o0.w = pack_bf16(a[6], a[7]);
    o1.x = pack_bf16(a[8], a[9]);
    o1.y = pack_bf16(a[10], a[11]);
    o1.z = pack_bf16(a[12], a[13]);
    o1.w = pack_bf16(a[14], a[15]);
    uint4* dst = (uint4*)(m_all + (size_t)r * (DD / 2));
    dst[2 * l] = o0;
    dst[2 * l + 1] = o1;
}

// One block per batch: stream m_all[b] (51.2 KB, coalesced) into LDS, load
// u0, run 3 fused hops, write uT column. (Known-good r0 hop pipeline.)
__global__ __launch_bounds__(512) void k_hops(const unsigned* __restrict__ m_all,
                                              const float* __restrict__ u0_all,
                                              const float* __restrict__ Hw,
                                              float* __restrict__ uT) {
    __shared__ unsigned m_s[MM][DD / 2];  // packed bf16 pairs, 51.2 KB
    __shared__ float u_s[DD];
    __shared__ float p_s[MM];
    __shared__ float o_part[8][DD];
    __shared__ float red_s;

    int b = blockIdx.x;
    int tid = threadIdx.x;

    {
        const uint4* src = (const uint4*)(m_all + (size_t)b * MM * (DD / 2));
        uint4* dst = (uint4*)&m_s[0][0];
        for (int i = tid; i < MM * (DD / 2) / 4; i += 512) dst[i] = src[i];
    }
    if (tid < DD) u_s[tid] = u0_all[(size_t)b * DD + tid];
    __syncthreads();

    for (int hop = 0; hop < 3; ++hop) {
        // Phase 1: p[t] = m[t,:] . u — thread per row, rotated (conflict-free)
        if (tid < MM) {
            const float2* u2 = (const float2*)u_s;
            float acc = 0.f;
#pragma unroll 8
            for (int li = 0; li < 64; ++li) {
                int j = (tid + li) & 63;
                unsigned pv = m_s[tid][j];
                float2 uv = u2[j];
                acc += bflo(pv) * uv.x + bfhi(pv) * uv.y;
            }
            p_s[tid] = acc;
        }
        __syncthreads();
        // Softmax over 200 (wave 0; 1/sum deferred to phase 3)
        if (tid < 64) {
            float v0 = p_s[tid], v1 = p_s[tid + 64], v2 = p_s[tid + 128];
            float v3 = (tid < 8) ? p_s[tid + 192] : -1e30f;
            float mx = fmaxf(fmaxf(v0, v1), fmaxf(v2, v3));
            for (int off = 32; off; off >>= 1) mx = fmaxf(mx, __shfl_down(mx, off));
            mx = __shfl(mx, 0);
            float e0 = __expf(v0 - mx), e1 = __expf(v1 - mx), e2 = __expf(v2 - mx);
            float e3 = (tid < 8) ? __expf(v3 - mx) : 0.f;
            float sm = e0 + e1 + e2 + e3;
            for (int off = 32; off; off >>= 1) sm += __shfl_down(sm, off);
            p_s[tid] = e0;
            p_s[tid + 64] = e1;
            p_s[tid + 128] = e2;
            if (tid < 8) p_s[tid + 192] = e3;
            if (tid == 0) red_s = 1.f / __shfl(sm, 0);
        }
        __syncthreads();
        // Phase 2: o[d] = sum_mm e[mm]*m[mm,d], mm split 8 ways
        {
            int c = tid & 63, h = tid >> 6;
            int mm0 = h * 25;
            float ax = 0.f, ay = 0.f;
#pragma unroll 5
            for (int k = 0; k < 25; ++k) {
                unsigned pv = m_s[mm0 + k][c];
                float p = p_s[mm0 + k];
                ax = fmaf(p, bflo(pv), ax);
                ay = fmaf(p, bfhi(pv), ay);
            }
            o_part[h][2 * c] = ax;
            o_part[h][2 * c + 1] = ay;
        }
        __syncthreads();
        // Phase 3: u'[d] = tanh( Hw[d,:] . u + inv * o[d] )
        float u_new = 0.f;
        if (tid < DD) {
            float o = 0.f;
#pragma unroll
            for (int h = 0; h < 8; ++h) o += o_part[h][tid];
            float acc = o * red_s;
            const float4* hrow = (const float4*)(Hw + tid * DD);
            const float4* u4 = (const float4*)u_s;
#pragma unroll 8
            for (int j = 0; j < DD / 4; ++j) {
                float4 hv = hrow[j];
                float4 uv = u4[j];
                acc += hv.x * uv.x + hv.y * uv.y + hv.z * uv.z + hv.w * uv.w;
            }
            u_new = tanhf(acc);
        }
        __syncthreads();
        if (tid < DD) u_s[tid] = u_new;
        __syncthreads();
    }
    if (tid < DD) uT[tid * BB + b] = u_s[tid];
}

// logits[b,c] = u[b,:] . cand_sum[c,:]. Grid (157, 4): block = 32 batches x
// 64 cands, 256 threads, thread = 1-batch x 8-cand tile. 628 blocks = 2.45
// waves/SIMD (r5: proven +3.6 us over the 157-block version). Cand tile
// transposed to k-major in LDS (pad 68); u read is one coalesced 128 B line
// per wave-half (uT is [d][B], L2-resident).
__global__ __launch_bounds__(256) void k_logits(const float* __restrict__ uT,
                                                const float* __restrict__ cs,
                                                float* __restrict__ out) {
    __shared__ float c_s[DD][LCT + 4];  // [k][c], 34.8 KB
    int c0 = blockIdx.x * LCT;
    int b0 = blockIdx.y * 32;
    int tid = threadIdx.x;
    {
        int c = tid >> 2, l = tid & 3;  // c 0..63, l = k-quarter
        int row = c0 + c;
        if (row >= NC) row = NC - 1;
        const float4* rp = (const float4*)(cs + (size_t)row * DD);
#pragma unroll
        for (int i = 0; i < 8; ++i) {
            int k = (l << 5) + (i << 2);
            float4 v = rp[(l << 3) + i];
            c_s[k][c] = v.x;
            c_s[k + 1][c] = v.y;
            c_s[k + 2][c] = v.z;
            c_s[k + 3][c] = v.w;
        }
    }
    __syncthreads();
    int tx = tid & 31, ty = tid >> 5;  // tx: batch, ty: 8-cand group
    const float* cb = &c_s[0][ty << 3];
    const float* up = uT + b0 + tx;
    float acc[8];
#pragma unroll
    for (int j = 0; j < 8; ++j) acc[j] = 0.f;
#pragma unroll 4
    for (int k = 0; k < DD; ++k) {
        float u = up[k * BB];
        float4 ca = *(const float4*)(cb + k * (LCT + 4));
        float4 cc = *(const float4*)(cb + k * (LCT + 4) + 4);
        acc[0] = fmaf(u, ca.x, acc[0]);
        acc[1] = fmaf(u, ca.y, acc[1]);
        acc[2] = fmaf(u, ca.z, acc[2]);
        acc[3] = fmaf(u, ca.w, acc[3]);
        acc[4] = fmaf(u, cc.x, acc[4]);
        acc[5] = fmaf(u, cc.y, acc[5]);
        acc[6] = fmaf(u, cc.z, acc[6]);
        acc[7] = fmaf(u, cc.w, acc[7]);
    }
    if (c0 + (ty << 3) < NC) {  // NC % 8 == 0 -> whole 8-chunk valid
        float* orow = out + (size_t)(b0 + tx) * NC + c0 + (ty << 3);
        ((float4*)orow)[0] = make_float4(acc[0], acc[1], acc[2], acc[3]);
        ((float4*)orow)[1] = make_float4(acc[4], acc[5], acc[6], acc[7]);
    }
}

extern "C" void kernel_launch(void* const* d_in, const int* in_sizes, int n_in,
                              void* d_out, int out_size, void* d_ws, size_t ws_size,
                              hipStream_t stream) {
    const int* stories = (const int*)d_in[0];       // [128,200,20] tokens
    const int* queries = (const int*)d_in[1];       // [128,20]
    const int* cands   = (const int*)d_in[2];       // [10000,10]
    const float* A  = (const float*)d_in[3];        // f32 [100000,128]
    const float* W  = (const float*)d_in[4];        // f32 [100000,128]
    const float* Hw = (const float*)d_in[5];        // f32 [128,128]
    float* out = (float*)d_out;                     // f32 [128,10000]

    unsigned char* Ai8 = (unsigned char*)d_ws;               // 12.8 MB
    float* sc = (float*)(Ai8 + (size_t)NV * DD);             // 400 KB
    float* cand_buf = sc + NV;                               // 5.12 MB
    float* uT_buf = cand_buf + (size_t)NC * DD;              // 64 KB
    float* u0_buf = uT_buf + (size_t)BB * DD;                // 64 KB
    unsigned* m_all = (unsigned*)(u0_buf + (size_t)BB * DD); // 6.55 MB (~25 MB total)

    k_prep<<<PREP_BLK, 256, 0, stream>>>(A, W, queries, cands, Ai8, sc,
                                         u0_buf, cand_buf);
    k_sgather<<<SG_BLK, 256, 0, stream>>>(stories, queries, Ai8, sc, m_all);
    k_hops<<<BB, 512, 0, stream>>>(m_all, u0_buf, Hw, uT_buf);
    dim3 lgrid((NC + LCT - 1) / LCT, 4);
    k_logits<<<lgrid, 256, 0, stream>>>(uT_buf, cand_buf, out);
}